// Round 3
// baseline (293.198 us; speedup 1.0000x reference)
//
#include <hip/hip_runtime.h>

#define D 128
#define NCG 4        // column groups (XCD-pinned via blockIdx % NCG)
#define CGW 32       // columns per group
#define CGU 16       // packed-uint (2 bf16) per row-slice

__device__ __forceinline__ float bf_lo(unsigned u) { return __uint_as_float(u << 16); }
__device__ __forceinline__ float bf_hi(unsigned u) { return __uint_as_float(u & 0xffff0000u); }

// ---------------------------------------------------------------------------
// Kernel A: f32 features -> bf16, re-laid out as Fb[cg][node][32 cols] so each
// column-group slice is a contiguous 3.2 MB region (per-XCD L2-resident).
// ---------------------------------------------------------------------------
__global__ __launch_bounds__(256) void cvt_bf16_kernel(const float* __restrict__ F,
                                                       unsigned* __restrict__ Fb,
                                                       int n_nodes) {
    int t = blockIdx.x * blockDim.x + threadIdx.x;  // one t per 4 columns
    int total = n_nodes * (D / 4);
    if (t >= total) return;
    int n = t >> 5;   // 32 quads per node row
    int q = t & 31;
    float4 v = reinterpret_cast<const float4*>(F)[t];
    unsigned b[4] = {__float_as_uint(v.x), __float_as_uint(v.y),
                     __float_as_uint(v.z), __float_as_uint(v.w)};
#pragma unroll
    for (int k = 0; k < 4; ++k)  // RNE to bf16
        b[k] = (b[k] + 0x7fffu + ((b[k] >> 16) & 1u)) >> 16;
    uint2 o = {b[0] | (b[1] << 16), b[2] | (b[3] << 16)};
    int cg = q >> 3;  // 8 quads per 32-col slice
    int qq = q & 7;
    reinterpret_cast<uint2*>(Fb + (size_t)(cg * n_nodes + n) * CGU)[qq] = o;
}

// ---------------------------------------------------------------------------
// Kernel 0: segment start offsets from sorted node_idx.
// ---------------------------------------------------------------------------
__global__ void seg_offsets_kernel(const int* __restrict__ node_idx,
                                   int* __restrict__ offs,
                                   int n_pairs, int n_nodes) {
    int p = blockIdx.x * blockDim.x + threadIdx.x;
    if (p >= n_pairs) return;
    int cur  = node_idx[p];
    int prev = (p == 0) ? -1 : node_idx[p - 1];
    for (int n = prev + 1; n <= cur; ++n) offs[n] = p;
    if (p == n_pairs - 1) {
        for (int n = cur + 1; n <= n_nodes; ++n) offs[n] = n_pairs;
    }
}

// ---------------------------------------------------------------------------
// Kernel 1: column-sliced gather+segment-sum. Block = (node, cg); cg pinned to
// XCD pair {cg, cg+4} by dispatch round-robin -> 3.2 MB slice stays in L2.
// 256 thr = 32 groups x 8 lanes; lane loads uint2 (4 bf16) of its row slice.
// Index arrays loaded non-temporally (streaming; don't evict the slice).
// ---------------------------------------------------------------------------
__global__ __launch_bounds__(256) void aggregate_kernel(
    const unsigned* __restrict__ Fb, const float* __restrict__ pw,
    const int* __restrict__ pi, const int* __restrict__ pj,
    const int* __restrict__ offs, float* __restrict__ agg, int n_nodes) {
    const int b  = blockIdx.x;
    const int cg = b & (NCG - 1);
    const int n  = b >> 2;
    const int start = offs[n];
    const int end   = offs[n + 1];
    const int lane  = threadIdx.x & 7;
    const int g     = threadIdx.x >> 3;

    const unsigned* __restrict__ base = Fb + (size_t)cg * n_nodes * CGU + lane * 2;

    float a0 = 0.f, a1 = 0.f, a2 = 0.f, a3 = 0.f;
    for (int p = start + g; p < end; p += 32) {
        const int   i = __builtin_nontemporal_load(pi + p);
        const int   j = __builtin_nontemporal_load(pj + p);
        const float w = __builtin_nontemporal_load(pw + p);
        const uint2 ui = *reinterpret_cast<const uint2*>(base + (size_t)i * CGU);
        const uint2 uj = *reinterpret_cast<const uint2*>(base + (size_t)j * CGU);
        a0 += (bf_lo(ui.x) + bf_lo(uj.x)) * w;
        a1 += (bf_hi(ui.x) + bf_hi(uj.x)) * w;
        a2 += (bf_lo(ui.y) + bf_lo(uj.y)) * w;
        a3 += (bf_hi(ui.y) + bf_hi(uj.y)) * w;
    }

    __shared__ float red[32][CGW + 1];
    red[g][lane * 4 + 0] = a0;
    red[g][lane * 4 + 1] = a1;
    red[g][lane * 4 + 2] = a2;
    red[g][lane * 4 + 3] = a3;
    __syncthreads();

    __shared__ float red2[8][CGW + 1];
    const int c = threadIdx.x & 31;
    const int q = threadIdx.x >> 5;
    red2[q][c] = red[q * 4 + 0][c] + red[q * 4 + 1][c] +
                 red[q * 4 + 2][c] + red[q * 4 + 3][c];
    __syncthreads();
    if (threadIdx.x < CGW) {
        float s = 0.f;
#pragma unroll
        for (int k = 0; k < 8; ++k) s += red2[k][c];
        __builtin_nontemporal_store(s, &agg[(size_t)n * D + cg * CGW + c]);
    }
}

// ---------------------------------------------------------------------------
// Kernel 2: out = agg @ W + bias.  M x 128 @ 128 x 128. (unchanged)
// ---------------------------------------------------------------------------
__global__ __launch_bounds__(256) void proj_kernel(
    const float* __restrict__ agg, const float* __restrict__ W,
    const float* __restrict__ bias, float* __restrict__ out, int M) {
    __shared__ float Wl[D * D];
    __shared__ float Al[64 * D];
    const int tid = threadIdx.x;

    for (int t = tid; t < D * D / 4; t += 256)
        reinterpret_cast<float4*>(Wl)[t] = reinterpret_cast<const float4*>(W)[t];

    const int row0 = blockIdx.x * 64;
    for (int t = tid; t < 64 * D / 4; t += 256) {
        const int r = row0 + (t >> 5);
        float4 v = make_float4(0.f, 0.f, 0.f, 0.f);
        if (r < M) v = reinterpret_cast<const float4*>(agg)[(size_t)row0 * (D / 4) + t];
        reinterpret_cast<float4*>(Al)[t] = v;
    }
    __syncthreads();

    const int tcol = tid & 31;
    const int trow = tid >> 5;
    float acc[8][4];
#pragma unroll
    for (int r = 0; r < 8; ++r)
#pragma unroll
        for (int c2 = 0; c2 < 4; ++c2) acc[r][c2] = 0.f;

    for (int d = 0; d < D; ++d) {
        const float4 wv = *reinterpret_cast<const float4*>(&Wl[d * D + tcol * 4]);
#pragma unroll
        for (int r = 0; r < 8; ++r) {
            const float a = Al[(trow * 8 + r) * D + d];
            acc[r][0] += a * wv.x;
            acc[r][1] += a * wv.y;
            acc[r][2] += a * wv.z;
            acc[r][3] += a * wv.w;
        }
    }

    const float4 bv = *reinterpret_cast<const float4*>(&bias[tcol * 4]);
#pragma unroll
    for (int r = 0; r < 8; ++r) {
        const int row = row0 + trow * 8 + r;
        if (row < M) {
            float4 o;
            o.x = acc[r][0] + bv.x;
            o.y = acc[r][1] + bv.y;
            o.z = acc[r][2] + bv.z;
            o.w = acc[r][3] + bv.w;
            *reinterpret_cast<float4*>(&out[(size_t)row * D + tcol * 4]) = o;
        }
    }
}

// ---------------------------------------------------------------------------
extern "C" void kernel_launch(void* const* d_in, const int* in_sizes, int n_in,
                              void* d_out, int out_size, void* d_ws, size_t ws_size,
                              hipStream_t stream) {
    const float* F    = (const float*)d_in[0];
    const float* pw   = (const float*)d_in[1];
    const float* W    = (const float*)d_in[2];
    const float* bias = (const float*)d_in[3];
    const int*   pi   = (const int*)d_in[4];
    const int*   pj   = (const int*)d_in[5];
    const int*   nidx = (const int*)d_in[6];
    float* out = (float*)d_out;

    const int n_pairs = in_sizes[1];
    const int n_nodes = in_sizes[0] / D;

    const size_t agg_bytes  = (size_t)n_nodes * D * 4;
    const size_t offs_bytes = (size_t)(n_nodes + 1) * 4;
    const size_t fb_bytes   = (size_t)n_nodes * D * 2;

    float* agg  = (float*)d_ws;
    int*   offs = (int*)((char*)d_ws + agg_bytes);
    unsigned* Fb;
    size_t used = agg_bytes + ((offs_bytes + 255) & ~(size_t)255);
    if (ws_size >= used + fb_bytes) {
        Fb = (unsigned*)((char*)d_ws + used);
    } else {
        Fb = (unsigned*)d_out;  // proj overwrites out last; Fb dead by then
    }

    const int nq = n_nodes * (D / 4);
    cvt_bf16_kernel<<<(nq + 255) / 256, 256, 0, stream>>>(F, Fb, n_nodes);
    seg_offsets_kernel<<<(n_pairs + 255) / 256, 256, 0, stream>>>(nidx, offs, n_pairs, n_nodes);
    aggregate_kernel<<<n_nodes * NCG, 256, 0, stream>>>(Fb, pw, pi, pj, offs, agg, n_nodes);
    proj_kernel<<<(n_nodes + 63) / 64, 256, 0, stream>>>(agg, W, bias, out, n_nodes);
}

// Round 4
// 240.761 us; speedup vs baseline: 1.2178x; 1.2178x over previous
//
#include <hip/hip_runtime.h>

#define D 128
#define NCG 4        // column groups (XCD-pinned via blockIdx % NCG)
#define CGW 32       // columns per group
#define CGU 16       // packed-uint (2 bf16 each) per row-slice

__device__ __forceinline__ float bf_lo(unsigned u) { return __uint_as_float(u << 16); }
__device__ __forceinline__ float bf_hi(unsigned u) { return __uint_as_float(u & 0xffff0000u); }

// ---------------------------------------------------------------------------
// Kernel A: f32 features -> bf16, laid out Fb[cg][node][32 cols] (3.2 MB/slice).
// ---------------------------------------------------------------------------
__global__ __launch_bounds__(256) void cvt_bf16_kernel(const float* __restrict__ F,
                                                       unsigned* __restrict__ Fb,
                                                       int n_nodes) {
    int t = blockIdx.x * blockDim.x + threadIdx.x;  // one t per 4 columns
    int total = n_nodes * (D / 4);
    if (t >= total) return;
    int n = t >> 5;
    int q = t & 31;
    float4 v = reinterpret_cast<const float4*>(F)[t];
    unsigned b[4] = {__float_as_uint(v.x), __float_as_uint(v.y),
                     __float_as_uint(v.z), __float_as_uint(v.w)};
#pragma unroll
    for (int k = 0; k < 4; ++k)  // RNE to bf16
        b[k] = (b[k] + 0x7fffu + ((b[k] >> 16) & 1u)) >> 16;
    uint2 o = {b[0] | (b[1] << 16), b[2] | (b[3] << 16)};
    int cg = q >> 3;
    int qq = q & 7;
    reinterpret_cast<uint2*>(Fb + (size_t)(cg * n_nodes + n) * CGU)[qq] = o;
}

// ---------------------------------------------------------------------------
// Kernel 0: segment start offsets from sorted node_idx.
// ---------------------------------------------------------------------------
__global__ void seg_offsets_kernel(const int* __restrict__ node_idx,
                                   int* __restrict__ offs,
                                   int n_pairs, int n_nodes) {
    int p = blockIdx.x * blockDim.x + threadIdx.x;
    if (p >= n_pairs) return;
    int cur  = node_idx[p];
    int prev = (p == 0) ? -1 : node_idx[p - 1];
    for (int n = prev + 1; n <= cur; ++n) offs[n] = p;
    if (p == n_pairs - 1) {
        for (int n = cur + 1; n <= n_nodes; ++n) offs[n] = n_pairs;
    }
}

// ---------------------------------------------------------------------------
// Kernel 1: wave-per-(node, cg). cg = blockIdx%4 -> XCD-pinned 3.2 MB slice
// stays L2-resident (validated R3: fetch 306->91 MB). Wave = 8 groups x 8
// lanes; group g takes pairs start+g, start+g+8, ... ; lane loads uint2
// (4 bf16 cols). Cross-group reduce via 3-step shfl_xor butterfly — no LDS,
// no __syncthreads, no per-block epilogue.
// ---------------------------------------------------------------------------
__global__ __launch_bounds__(256) void aggregate_kernel(
    const unsigned* __restrict__ Fb, const float* __restrict__ pw,
    const int* __restrict__ pi, const int* __restrict__ pj,
    const int* __restrict__ offs, float* __restrict__ agg, int n_nodes) {
    const int cg  = blockIdx.x & (NCG - 1);
    const int wid = threadIdx.x >> 6;
    const int n   = (blockIdx.x >> 2) * 4 + wid;
    if (n >= n_nodes) return;
    const int start = offs[n];
    const int end   = offs[n + 1];
    const int lane  = threadIdx.x & 7;        // lane within 8-lane group
    const int g     = (threadIdx.x >> 3) & 7; // group within wave

    const unsigned* __restrict__ base = Fb + (size_t)cg * n_nodes * CGU + lane * 2;

    float a0 = 0.f, a1 = 0.f, a2 = 0.f, a3 = 0.f;
    for (int p = start + g; p < end; p += 8) {
        const int   i = __builtin_nontemporal_load(pi + p);
        const int   j = __builtin_nontemporal_load(pj + p);
        const float w = __builtin_nontemporal_load(pw + p);
        const uint2 ui = *reinterpret_cast<const uint2*>(base + (size_t)i * CGU);
        const uint2 uj = *reinterpret_cast<const uint2*>(base + (size_t)j * CGU);
        a0 += (bf_lo(ui.x) + bf_lo(uj.x)) * w;
        a1 += (bf_hi(ui.x) + bf_hi(uj.x)) * w;
        a2 += (bf_lo(ui.y) + bf_lo(uj.y)) * w;
        a3 += (bf_hi(ui.y) + bf_hi(uj.y)) * w;
    }

    // butterfly across the 8 groups (lane bits 3,4,5) — all lanes end with totals
    a0 += __shfl_xor(a0, 8);  a1 += __shfl_xor(a1, 8);
    a2 += __shfl_xor(a2, 8);  a3 += __shfl_xor(a3, 8);
    a0 += __shfl_xor(a0, 16); a1 += __shfl_xor(a1, 16);
    a2 += __shfl_xor(a2, 16); a3 += __shfl_xor(a3, 16);
    a0 += __shfl_xor(a0, 32); a1 += __shfl_xor(a1, 32);
    a2 += __shfl_xor(a2, 32); a3 += __shfl_xor(a3, 32);

    if (g == 0) {
        float4 o = make_float4(a0, a1, a2, a3);
        *reinterpret_cast<float4*>(&agg[(size_t)n * D + cg * CGW + lane * 4]) = o;
    }
}

// ---------------------------------------------------------------------------
// Kernel 2: out = agg @ W + bias.  M x 128 @ 128 x 128. (unchanged)
// ---------------------------------------------------------------------------
__global__ __launch_bounds__(256) void proj_kernel(
    const float* __restrict__ agg, const float* __restrict__ W,
    const float* __restrict__ bias, float* __restrict__ out, int M) {
    __shared__ float Wl[D * D];
    __shared__ float Al[64 * D];
    const int tid = threadIdx.x;

    for (int t = tid; t < D * D / 4; t += 256)
        reinterpret_cast<float4*>(Wl)[t] = reinterpret_cast<const float4*>(W)[t];

    const int row0 = blockIdx.x * 64;
    for (int t = tid; t < 64 * D / 4; t += 256) {
        const int r = row0 + (t >> 5);
        float4 v = make_float4(0.f, 0.f, 0.f, 0.f);
        if (r < M) v = reinterpret_cast<const float4*>(agg)[(size_t)row0 * (D / 4) + t];
        reinterpret_cast<float4*>(Al)[t] = v;
    }
    __syncthreads();

    const int tcol = tid & 31;
    const int trow = tid >> 5;
    float acc[8][4];
#pragma unroll
    for (int r = 0; r < 8; ++r)
#pragma unroll
        for (int c2 = 0; c2 < 4; ++c2) acc[r][c2] = 0.f;

    for (int d = 0; d < D; ++d) {
        const float4 wv = *reinterpret_cast<const float4*>(&Wl[d * D + tcol * 4]);
#pragma unroll
        for (int r = 0; r < 8; ++r) {
            const float a = Al[(trow * 8 + r) * D + d];
            acc[r][0] += a * wv.x;
            acc[r][1] += a * wv.y;
            acc[r][2] += a * wv.z;
            acc[r][3] += a * wv.w;
        }
    }

    const float4 bv = *reinterpret_cast<const float4*>(&bias[tcol * 4]);
#pragma unroll
    for (int r = 0; r < 8; ++r) {
        const int row = row0 + trow * 8 + r;
        if (row < M) {
            float4 o;
            o.x = acc[r][0] + bv.x;
            o.y = acc[r][1] + bv.y;
            o.z = acc[r][2] + bv.z;
            o.w = acc[r][3] + bv.w;
            *reinterpret_cast<float4*>(&out[(size_t)row * D + tcol * 4]) = o;
        }
    }
}

// ---------------------------------------------------------------------------
extern "C" void kernel_launch(void* const* d_in, const int* in_sizes, int n_in,
                              void* d_out, int out_size, void* d_ws, size_t ws_size,
                              hipStream_t stream) {
    const float* F    = (const float*)d_in[0];
    const float* pw   = (const float*)d_in[1];
    const float* W    = (const float*)d_in[2];
    const float* bias = (const float*)d_in[3];
    const int*   pi   = (const int*)d_in[4];
    const int*   pj   = (const int*)d_in[5];
    const int*   nidx = (const int*)d_in[6];
    float* out = (float*)d_out;

    const int n_pairs = in_sizes[1];
    const int n_nodes = in_sizes[0] / D;

    const size_t agg_bytes  = (size_t)n_nodes * D * 4;
    const size_t offs_bytes = (size_t)(n_nodes + 1) * 4;
    const size_t fb_bytes   = (size_t)n_nodes * D * 2;

    float* agg  = (float*)d_ws;
    int*   offs = (int*)((char*)d_ws + agg_bytes);
    unsigned* Fb;
    size_t used = agg_bytes + ((offs_bytes + 255) & ~(size_t)255);
    if (ws_size >= used + fb_bytes) {
        Fb = (unsigned*)((char*)d_ws + used);
    } else {
        Fb = (unsigned*)d_out;  // proj overwrites out last; Fb dead by then
    }

    const int nq = n_nodes * (D / 4);
    cvt_bf16_kernel<<<(nq + 255) / 256, 256, 0, stream>>>(F, Fb, n_nodes);
    seg_offsets_kernel<<<(n_pairs + 255) / 256, 256, 0, stream>>>(nidx, offs, n_pairs, n_nodes);
    const int nb = (n_nodes + 3) / 4;  // 4 nodes (waves) per block
    aggregate_kernel<<<nb * NCG, 256, 0, stream>>>(Fb, pw, pi, pj, offs, agg, n_nodes);
    proj_kernel<<<(n_nodes + 63) / 64, 256, 0, stream>>>(agg, W, bias, out, n_nodes);
}

// Round 5
// 123.067 us; speedup vs baseline: 2.3824x; 1.9564x over previous
//
#include <hip/hip_runtime.h>

#define D 128

__device__ __forceinline__ float bf_lo(unsigned u) { return __uint_as_float(u << 16); }
__device__ __forceinline__ float bf_hi(unsigned u) { return __uint_as_float(u & 0xffff0000u); }
__device__ __forceinline__ unsigned pack_bf16(float a, float b) {
    unsigned ua = __float_as_uint(a), ub = __float_as_uint(b);
    ua = (ua + 0x7fffu + ((ua >> 16) & 1u)) >> 16;   // RNE
    ub = (ub + 0x7fffu + ((ub >> 16) & 1u)) >> 16;
    return ua | (ub << 16);
}

// ---------------------------------------------------------------------------
// features f32 -> bf16, plain [node][128] layout (a 128B line = one half-row
// = one cg slice; NCG=2 needs no relayout for XCD-L2 pinning).
// ---------------------------------------------------------------------------
__global__ __launch_bounds__(256) void cvt_bf16_kernel(const float* __restrict__ F,
                                                       unsigned* __restrict__ Fb, int n4) {
    int t = blockIdx.x * 256 + threadIdx.x;
    if (t >= n4) return;
    float4 v = reinterpret_cast<const float4*>(F)[t];
    uint2 o = {pack_bf16(v.x, v.y), pack_bf16(v.z, v.w)};
    reinterpret_cast<uint2*>(Fb)[t] = o;
}

// ---------------------------------------------------------------------------
// W f32 [128][128] -> packed bf16 uints [128][64]
// ---------------------------------------------------------------------------
__global__ __launch_bounds__(256) void wcvt_kernel(const float* __restrict__ W,
                                                   unsigned* __restrict__ Wb) {
    int t = blockIdx.x * 256 + threadIdx.x;  // one t per uint (2 cols)
    if (t >= D * D / 2) return;
    Wb[t] = pack_bf16(W[2 * t], W[2 * t + 1]);
}

// ---------------------------------------------------------------------------
// pack (i,j,w) -> uint2 record + segment offsets from sorted node_idx.
// ---------------------------------------------------------------------------
__global__ void prepack_kernel(const int* __restrict__ pi, const int* __restrict__ pj,
                               const float* __restrict__ pw, const int* __restrict__ nidx,
                               uint2* __restrict__ rec, int* __restrict__ offs,
                               int n_pairs, int n_nodes) {
    int p = blockIdx.x * 256 + threadIdx.x;
    if (p >= n_pairs) return;
    rec[p] = make_uint2((unsigned)pi[p] | ((unsigned)pj[p] << 16), __float_as_uint(pw[p]));
    int cur  = nidx[p];
    int prev = p ? nidx[p - 1] : -1;
    for (int n = prev + 1; n <= cur; ++n) offs[n] = p;
    if (p == n_pairs - 1)
        for (int n = cur + 1; n <= n_nodes; ++n) offs[n] = n_pairs;
}

// ---------------------------------------------------------------------------
// Aggregate: wave per (node, half). cg = blockIdx&1 -> XCD-pinned 6.4 MB
// half-column slice (alternating 128B lines). Wave = 8 groups x 8 lanes;
// lane loads uint4 = 8 bf16 cols = 16 B (the request-rate sweet spot).
// One packed 8B record load per pair (group-uniform). Butterfly reduce over
// lane bits 3..5 -> zero LDS, zero syncthreads. Output stored as bf16.
// ---------------------------------------------------------------------------
__global__ __launch_bounds__(256) void aggregate_kernel(
    const unsigned* __restrict__ Fb, const uint2* __restrict__ rec,
    const int* __restrict__ offs, unsigned* __restrict__ aggb, int n_nodes) {
    const int cg  = blockIdx.x & 1;
    const int wid = threadIdx.x >> 6;
    const int n   = (blockIdx.x >> 1) * 4 + wid;
    if (n >= n_nodes) return;
    const int start = offs[n];
    const int end   = offs[n + 1];
    const int lane  = threadIdx.x & 7;        // 8 lanes x 16B = 128B half-row
    const int g     = (threadIdx.x >> 3) & 7; // 8 groups, stride 8 over pairs

    const unsigned* __restrict__ base = Fb + cg * 32 + lane * 4;  // uint units

    float a0 = 0.f, a1 = 0.f, a2 = 0.f, a3 = 0.f;
    float a4 = 0.f, a5 = 0.f, a6 = 0.f, a7 = 0.f;
    for (int p = start + g; p < end; p += 8) {
        const uint2 r = rec[p];
        const unsigned i = r.x & 0xffffu;
        const unsigned j = r.x >> 16;
        const float  w = __uint_as_float(r.y);
        const uint4 ui = *reinterpret_cast<const uint4*>(base + (size_t)i * 64);
        const uint4 uj = *reinterpret_cast<const uint4*>(base + (size_t)j * 64);
        a0 += (bf_lo(ui.x) + bf_lo(uj.x)) * w;
        a1 += (bf_hi(ui.x) + bf_hi(uj.x)) * w;
        a2 += (bf_lo(ui.y) + bf_lo(uj.y)) * w;
        a3 += (bf_hi(ui.y) + bf_hi(uj.y)) * w;
        a4 += (bf_lo(ui.z) + bf_lo(uj.z)) * w;
        a5 += (bf_hi(ui.z) + bf_hi(uj.z)) * w;
        a6 += (bf_lo(ui.w) + bf_lo(uj.w)) * w;
        a7 += (bf_hi(ui.w) + bf_hi(uj.w)) * w;
    }

#pragma unroll
    for (int m = 8; m <= 32; m <<= 1) {
        a0 += __shfl_xor(a0, m); a1 += __shfl_xor(a1, m);
        a2 += __shfl_xor(a2, m); a3 += __shfl_xor(a3, m);
        a4 += __shfl_xor(a4, m); a5 += __shfl_xor(a5, m);
        a6 += __shfl_xor(a6, m); a7 += __shfl_xor(a7, m);
    }

    if (g == 0) {
        uint4 o = {pack_bf16(a0, a1), pack_bf16(a2, a3),
                   pack_bf16(a4, a5), pack_bf16(a6, a7)};
        *reinterpret_cast<uint4*>(aggb + (size_t)n * 64 + cg * 32 + lane * 4) = o;
    }
}

// ---------------------------------------------------------------------------
// Proj: out = aggb(bf16) @ Wb(bf16) + bias, f32 accumulate.
// 64 rows/block, LDS = Al f32 32KB + Wl packed-bf16 32KB = 64KB (2 blocks/CU).
// ---------------------------------------------------------------------------
__global__ __launch_bounds__(256) void proj_kernel(
    const unsigned* __restrict__ aggb, const unsigned* __restrict__ Wb,
    const float* __restrict__ bias, float* __restrict__ out, int M) {
    __shared__ float    Al[64 * D];        // 32 KB
    __shared__ unsigned Wl[D * (D / 2)];   // 32 KB packed bf16
    const int tid = threadIdx.x;

    // stage W (2048 uint4 / 256 thr = 8 each)
    for (int t = tid; t < D * (D / 2) / 4; t += 256)
        reinterpret_cast<uint4*>(Wl)[t] = reinterpret_cast<const uint4*>(Wb)[t];

    const int row0 = blockIdx.x * 64;
    // stage A: 64 rows x 16 uint4 (8 bf16 each) = 1024 / 256 = 4 each
    for (int t = tid; t < 64 * 16; t += 256) {
        const int r = t >> 4, q = t & 15;
        uint4 v = {0u, 0u, 0u, 0u};
        if (row0 + r < M)
            v = reinterpret_cast<const uint4*>(aggb)[(size_t)(row0 + r) * 16 + q];
        float* dst = &Al[r * D + q * 8];
        dst[0] = bf_lo(v.x); dst[1] = bf_hi(v.x);
        dst[2] = bf_lo(v.y); dst[3] = bf_hi(v.y);
        dst[4] = bf_lo(v.z); dst[5] = bf_hi(v.z);
        dst[6] = bf_lo(v.w); dst[7] = bf_hi(v.w);
    }
    __syncthreads();

    const int tcol = tid & 31;   // 32 col-groups of 4
    const int trow = tid >> 5;   // 8 row-groups of 8
    float acc[8][4];
#pragma unroll
    for (int r = 0; r < 8; ++r)
#pragma unroll
        for (int c = 0; c < 4; ++c) acc[r][c] = 0.f;

    for (int d = 0; d < D; ++d) {
        const uint2 wu = *reinterpret_cast<const uint2*>(&Wl[d * (D / 2) + tcol * 2]);
        const float w0 = bf_lo(wu.x), w1 = bf_hi(wu.x);
        const float w2 = bf_lo(wu.y), w3 = bf_hi(wu.y);
#pragma unroll
        for (int r = 0; r < 8; ++r) {
            const float a = Al[(trow * 8 + r) * D + d];
            acc[r][0] += a * w0;
            acc[r][1] += a * w1;
            acc[r][2] += a * w2;
            acc[r][3] += a * w3;
        }
    }

    const float4 bv = *reinterpret_cast<const float4*>(&bias[tcol * 4]);
#pragma unroll
    for (int r = 0; r < 8; ++r) {
        const int row = row0 + trow * 8 + r;
        if (row < M) {
            float4 o;
            o.x = acc[r][0] + bv.x;
            o.y = acc[r][1] + bv.y;
            o.z = acc[r][2] + bv.z;
            o.w = acc[r][3] + bv.w;
            *reinterpret_cast<float4*>(&out[(size_t)row * D + tcol * 4]) = o;
        }
    }
}

// ---------------------------------------------------------------------------
extern "C" void kernel_launch(void* const* d_in, const int* in_sizes, int n_in,
                              void* d_out, int out_size, void* d_ws, size_t ws_size,
                              hipStream_t stream) {
    const float* F    = (const float*)d_in[0];
    const float* pw   = (const float*)d_in[1];
    const float* W    = (const float*)d_in[2];
    const float* bias = (const float*)d_in[3];
    const int*   pi   = (const int*)d_in[4];
    const int*   pj   = (const int*)d_in[5];
    const int*   nidx = (const int*)d_in[6];
    float* out = (float*)d_out;

    const int n_pairs = in_sizes[1];
    const int n_nodes = in_sizes[0] / D;

    // ws layout: aggb (bf16) | offs | rec | Wb | [Fb]
    const size_t aggb_bytes = (size_t)n_nodes * D * 2;
    const size_t offs_bytes = ((size_t)(n_nodes + 1) * 4 + 255) & ~(size_t)255;
    const size_t rec_bytes  = (size_t)n_pairs * 8;
    const size_t wb_bytes   = (size_t)D * (D / 2) * 4;
    const size_t fb_bytes   = (size_t)n_nodes * D * 2;

    unsigned* aggb = (unsigned*)d_ws;
    int*      offs = (int*)((char*)d_ws + aggb_bytes);
    uint2*    rec  = (uint2*)((char*)d_ws + aggb_bytes + offs_bytes);
    unsigned* Wb   = (unsigned*)((char*)d_ws + aggb_bytes + offs_bytes + rec_bytes);
    size_t used = aggb_bytes + offs_bytes + rec_bytes + wb_bytes;
    unsigned* Fb = (ws_size >= used + fb_bytes)
                 ? (unsigned*)((char*)d_ws + used)
                 : (unsigned*)d_out;  // proj writes out last; Fb dead by then

    const int n4 = n_nodes * D / 4;
    cvt_bf16_kernel<<<(n4 + 255) / 256, 256, 0, stream>>>(F, Fb, n4);
    wcvt_kernel<<<(D * D / 2 + 255) / 256, 256, 0, stream>>>(W, Wb);
    prepack_kernel<<<(n_pairs + 255) / 256, 256, 0, stream>>>(pi, pj, pw, nidx, rec, offs,
                                                              n_pairs, n_nodes);
    const int nb = (n_nodes + 3) / 4;  // 4 node-waves per block
    aggregate_kernel<<<nb * 2, 256, 0, stream>>>(Fb, rec, offs, aggb, n_nodes);
    proj_kernel<<<(n_nodes + 63) / 64, 256, 0, stream>>>(aggb, Wb, bias, out, n_nodes);
}

// Round 6
// 108.793 us; speedup vs baseline: 2.6950x; 1.1312x over previous
//
#include <hip/hip_runtime.h>

#define D 128

typedef __attribute__((ext_vector_type(8))) short short8;   // 8 bf16 (4 VGPRs)
typedef __attribute__((ext_vector_type(4))) float floatx4;  // MFMA acc

__device__ __forceinline__ float bf_lo(unsigned u) { return __uint_as_float(u << 16); }
__device__ __forceinline__ float bf_hi(unsigned u) { return __uint_as_float(u & 0xffff0000u); }
__device__ __forceinline__ unsigned pack_bf16(float a, float b) {
    unsigned ua = __float_as_uint(a), ub = __float_as_uint(b);
    ua = (ua + 0x7fffu + ((ua >> 16) & 1u)) >> 16;   // RNE
    ub = (ub + 0x7fffu + ((ub >> 16) & 1u)) >> 16;
    return ua | (ub << 16);
}

// ---------------------------------------------------------------------------
// Fused prep: [sec A] features f32->bf16 | [sec B] SoA (ij,w) + seg offsets |
// [sec C] W -> Wt bf16 transposed ([col][k] packed by k-pairs).
// ---------------------------------------------------------------------------
__global__ __launch_bounds__(256) void prep_kernel(
    const float* __restrict__ F, const float* __restrict__ pw,
    const float* __restrict__ W, const int* __restrict__ pi,
    const int* __restrict__ pj, const int* __restrict__ nidx,
    unsigned* __restrict__ Fb, unsigned* __restrict__ ij,
    float* __restrict__ wv, int* __restrict__ offs, unsigned* __restrict__ Wt,
    int n_nodes, int n_pairs) {
    const int B1 = (n_nodes * (D / 4) + 255) / 256;
    const int B2 = (n_pairs + 255) / 256;
    const int b = blockIdx.x;
    if (b < B1) {                       // features -> bf16
        int t = b * 256 + threadIdx.x;
        if (t >= n_nodes * (D / 4)) return;
        float4 v = reinterpret_cast<const float4*>(F)[t];
        uint2 o = {pack_bf16(v.x, v.y), pack_bf16(v.z, v.w)};
        reinterpret_cast<uint2*>(Fb)[t] = o;
    } else if (b < B1 + B2) {           // SoA records + offsets
        int p = (b - B1) * 256 + threadIdx.x;
        if (p >= n_pairs) return;
        ij[p] = (unsigned)pi[p] | ((unsigned)pj[p] << 16);
        wv[p] = pw[p];
        int cur  = nidx[p];
        int prev = p ? nidx[p - 1] : -1;
        for (int n = prev + 1; n <= cur; ++n) offs[n] = p;
        if (p == n_pairs - 1)
            for (int n = cur + 1; n <= n_nodes; ++n) offs[n] = n_pairs;
    } else {                            // Wt[c][kk] = pack(W[2kk][c], W[2kk+1][c])
        int t = (b - B1 - B2) * 256 + threadIdx.x;
        if (t >= D * (D / 2)) return;
        int c = t >> 6, kk = t & 63;
        Wt[t] = pack_bf16(W[(2 * kk) * D + c], W[(2 * kk + 1) * D + c]);
    }
}

// ---------------------------------------------------------------------------
// Aggregate: wave per (node, half-row cg). cg = blockIdx&1 -> XCD-pinned
// 6.4 MB slice (validated R3/R5). Wave = 8 groups x 8 lanes; lane gathers
// uint4 = 16B (8 bf16 cols). Records deduped: per 64-pair chunk each lane
// loads one SoA record, __shfl broadcasts per step -> rec lane-reqs / 8.
// Butterfly reduce, zero LDS / syncthreads. Output bf16.
// ---------------------------------------------------------------------------
__global__ __launch_bounds__(256) void aggregate_kernel(
    const unsigned* __restrict__ Fb, const unsigned* __restrict__ ij,
    const float* __restrict__ wv, const int* __restrict__ offs,
    unsigned* __restrict__ aggb, int n_nodes) {
    const int cg  = blockIdx.x & 1;
    const int wid = threadIdx.x >> 6;
    const int n   = (blockIdx.x >> 1) * 4 + wid;
    if (n >= n_nodes) return;
    const int start = offs[n];
    const int end   = offs[n + 1];
    const int lane  = threadIdx.x & 7;
    const int g     = (threadIdx.x >> 3) & 7;
    const int l64   = threadIdx.x & 63;

    const unsigned* __restrict__ base = Fb + cg * 32 + lane * 4;  // uint units

    float a0 = 0.f, a1 = 0.f, a2 = 0.f, a3 = 0.f;
    float a4 = 0.f, a5 = 0.f, a6 = 0.f, a7 = 0.f;

    for (int c0 = start; c0 < end; c0 += 64) {
        const int myp = c0 + l64;
        unsigned ijv = 0u;
        float    wvv = 0.f;
        if (myp < end) {
            ijv = __builtin_nontemporal_load(ij + myp);
            wvv = __builtin_nontemporal_load(wv + myp);
        }
        const int nsteps = min(8, (end - c0 + 7) >> 3);
        for (int s = 0; s < nsteps; ++s) {
            const int src = s * 8 + g;
            const unsigned r = __shfl(ijv, src);
            const float    w = __shfl(wvv, src);
            const int p = c0 + src;
            if (p < end) {
                const unsigned i = r & 0xffffu;
                const unsigned j = r >> 16;
                const uint4 ui = *reinterpret_cast<const uint4*>(base + (size_t)i * 64);
                const uint4 uj = *reinterpret_cast<const uint4*>(base + (size_t)j * 64);
                a0 += (bf_lo(ui.x) + bf_lo(uj.x)) * w;
                a1 += (bf_hi(ui.x) + bf_hi(uj.x)) * w;
                a2 += (bf_lo(ui.y) + bf_lo(uj.y)) * w;
                a3 += (bf_hi(ui.y) + bf_hi(uj.y)) * w;
                a4 += (bf_lo(ui.z) + bf_lo(uj.z)) * w;
                a5 += (bf_hi(ui.z) + bf_hi(uj.z)) * w;
                a6 += (bf_lo(ui.w) + bf_lo(uj.w)) * w;
                a7 += (bf_hi(ui.w) + bf_hi(uj.w)) * w;
            }
        }
    }

#pragma unroll
    for (int m = 8; m <= 32; m <<= 1) {
        a0 += __shfl_xor(a0, m); a1 += __shfl_xor(a1, m);
        a2 += __shfl_xor(a2, m); a3 += __shfl_xor(a3, m);
        a4 += __shfl_xor(a4, m); a5 += __shfl_xor(a5, m);
        a6 += __shfl_xor(a6, m); a7 += __shfl_xor(a7, m);
    }

    if (g == 0) {
        uint4 o = {pack_bf16(a0, a1), pack_bf16(a2, a3),
                   pack_bf16(a4, a5), pack_bf16(a6, a7)};
        *reinterpret_cast<uint4*>(aggb + (size_t)n * 64 + cg * 32 + lane * 4) = o;
    }
}

// ---------------------------------------------------------------------------
// Proj (MFMA): out = aggb(bf16) @ W + bias, f32 acc via mfma_f32_16x16x32_bf16.
// Block = 4 waves x 16 rows = 64 rows. Wave: 16(M) x 128(N), K=128 in 4 steps.
// A-frag: row=lane&15, k=(lane>>4)*8+e (k-consecutive -> uint4 of aggb row).
// B-frag: col=lane&15, same k -> uint4 of Wt[col] (k-major transposed W).
// C: col=lane&15, row=(lane>>4)*4+reg [verified m89 layout].
// ---------------------------------------------------------------------------
__global__ __launch_bounds__(256) void proj_kernel(
    const unsigned* __restrict__ aggb, const unsigned* __restrict__ Wt,
    const float* __restrict__ bias, float* __restrict__ out, int M) {
    const int wid = threadIdx.x >> 6;
    const int l   = threadIdx.x & 63;
    const int lr  = l & 15;       // A-row / B-col / C-col
    const int lk  = l >> 4;       // k-chunk (0..3)
    const int row_base = blockIdx.x * 64 + wid * 16;

    int arow = row_base + lr;
    if (arow >= M) arow = M - 1;  // clamp; stores are predicated

    const short8* __restrict__ A8 = reinterpret_cast<const short8*>(aggb);
    const short8* __restrict__ B8 = reinterpret_cast<const short8*>(Wt);

    floatx4 acc[8];
#pragma unroll
    for (int t = 0; t < 8; ++t) acc[t] = (floatx4){0.f, 0.f, 0.f, 0.f};

#pragma unroll
    for (int ks = 0; ks < 4; ++ks) {
        const short8 a = A8[(size_t)arow * 16 + ks * 4 + lk];
#pragma unroll
        for (int t = 0; t < 8; ++t) {
            const short8 bfr = B8[(size_t)(t * 16 + lr) * 16 + ks * 4 + lk];
            acc[t] = __builtin_amdgcn_mfma_f32_16x16x32_bf16(a, bfr, acc[t], 0, 0, 0);
        }
    }

#pragma unroll
    for (int t = 0; t < 8; ++t) {
        const float bcol = bias[t * 16 + lr];
#pragma unroll
        for (int r = 0; r < 4; ++r) {
            const int row = row_base + lk * 4 + r;
            if (row < M)
                out[(size_t)row * D + t * 16 + lr] = acc[t][r] + bcol;
        }
    }
}

// ---------------------------------------------------------------------------
extern "C" void kernel_launch(void* const* d_in, const int* in_sizes, int n_in,
                              void* d_out, int out_size, void* d_ws, size_t ws_size,
                              hipStream_t stream) {
    const float* F    = (const float*)d_in[0];
    const float* pw   = (const float*)d_in[1];
    const float* W    = (const float*)d_in[2];
    const float* bias = (const float*)d_in[3];
    const int*   pi   = (const int*)d_in[4];
    const int*   pj   = (const int*)d_in[5];
    const int*   nidx = (const int*)d_in[6];
    float* out = (float*)d_out;

    const int n_pairs = in_sizes[1];
    const int n_nodes = in_sizes[0] / D;

    // ws layout: aggb | offs | ij | wv | Wt | [Fb]
    const size_t aggb_bytes = (size_t)n_nodes * D * 2;
    const size_t offs_bytes = ((size_t)(n_nodes + 1) * 4 + 255) & ~(size_t)255;
    const size_t ij_bytes   = (size_t)n_pairs * 4;
    const size_t wv_bytes   = (size_t)n_pairs * 4;
    const size_t wt_bytes   = (size_t)D * (D / 2) * 4;
    const size_t fb_bytes   = (size_t)n_nodes * D * 2;

    char* p = (char*)d_ws;
    unsigned* aggb = (unsigned*)p;                 p += aggb_bytes;
    int*      offs = (int*)p;                      p += offs_bytes;
    unsigned* ij   = (unsigned*)p;                 p += ij_bytes;
    float*    wvv  = (float*)p;                    p += wv_bytes;
    unsigned* Wt   = (unsigned*)p;                 p += wt_bytes;
    size_t used = (size_t)(p - (char*)d_ws);
    unsigned* Fb = (ws_size >= used + fb_bytes)
                 ? (unsigned*)p
                 : (unsigned*)d_out;  // proj writes out last; Fb dead by then

    const int B1 = (n_nodes * (D / 4) + 255) / 256;
    const int B2 = (n_pairs + 255) / 256;
    const int B3 = (D * (D / 2) + 255) / 256;
    prep_kernel<<<B1 + B2 + B3, 256, 0, stream>>>(F, pw, W, pi, pj, nidx,
                                                  Fb, ij, wvv, offs, Wt,
                                                  n_nodes, n_pairs);
    const int nb = (n_nodes + 3) / 4;  // 4 node-waves per block
    aggregate_kernel<<<nb * 2, 256, 0, stream>>>(Fb, ij, wvv, offs, aggb, n_nodes);
    proj_kernel<<<(n_nodes + 63) / 64, 256, 0, stream>>>(aggb, Wt, bias, out, n_nodes);
}